// Round 9
// baseline (6781.870 us; speedup 1.0000x reference)
//
#include <hip/hip_runtime.h>

#define DN 128

__device__ __forceinline__ float bf2f(unsigned short u) {
    union { unsigned int i; float f; } v; v.i = ((unsigned int)u) << 16; return v.f;
}
__device__ __forceinline__ unsigned short f2bf(float f) {
    union { float f; unsigned int i; } v; v.f = f;
    unsigned int r = v.i + 0x7fffu + ((v.i >> 16) & 1u);
    return (unsigned short)(r >> 16);
}
__device__ __forceinline__ float lo16(unsigned int u) { return bf2f((unsigned short)(u & 0xffffu)); }
__device__ __forceinline__ float hi16(unsigned int u) { return bf2f((unsigned short)(u >> 16)); }
__device__ __forceinline__ unsigned int pack2(float x, float y) {
    return (unsigned int)f2bf(x) | ((unsigned int)f2bf(y) << 16);
}
__device__ __forceinline__ float ldx(const void* p, size_t i, int f32) {
    return f32 ? ((const float*)p)[i] : bf2f(((const unsigned short*)p)[i]);
}

__global__ void k_diag(unsigned short* out, int cnt, float val) {
    unsigned short v = f2bf(val);
    for (int i = blockIdx.x * blockDim.x + threadIdx.x; i < cnt; i += gridDim.x * blockDim.x)
        out[i] = v;
}

// ---- MFMA compile probe (launched on dead scratch; output never read) ----
typedef short s16x8 __attribute__((ext_vector_type(8)));
typedef float f32x4 __attribute__((ext_vector_type(4)));
__global__ void k_mfma_probe(float* outp) {
    s16x8 a = {0, 0, 0, 0, 0, 0, 0, 0};
    s16x8 b = a;
    f32x4 c = {0.f, 0.f, 0.f, 0.f};
    c = __builtin_amdgcn_mfma_f32_16x16x32_bf16(a, b, c, 0, 0, 0);
    if (threadIdx.x == 0) outp[0] = c[0];
}

// ---- dtype probes (flags pre-zeroed) ----
__global__ void k_probe(const void* x, const void* w, const int* e, int* flags) {
    int t = threadIdx.x;
    const unsigned short* xu = (const unsigned short*)x;
    for (int i = t; i < 100000; i += 256)
        if ((xu[i] & 0x7F80u) == 0x7F80u) { atomicOr(&flags[0], 1); break; }
    const unsigned short* wu = (const unsigned short*)w;
    for (int i = t; i < 16384; i += 256)
        if ((wu[i] & 0x7F80u) == 0x7F80u) { atomicOr(&flags[2], 1); break; }
    for (int i = t; i < 1000; i += 256)
        if (e[2 * i + 1] != 0) { atomicOr(&flags[1], 1); break; }
}

// ---- degree histogram ----
__global__ void k_deg(const int* e, const int* flags, int* deg, int E, int n) {
    int i = blockIdx.x * blockDim.x + threadIdx.x;
    if (i < E) {
        int is64 = (flags[1] == 0);
        int d = is64 ? e[2 * (E + i)] : e[E + i];
        if ((unsigned)d < (unsigned)n) atomicAdd(&deg[d], 1);
    }
}

// ---- exclusive scan (single block) ----
__global__ void k_scan(const int* deg, int* rowp, int n) {
    __shared__ int buf[1024];
    __shared__ int carry;
    if (threadIdx.x == 0) carry = 0;
    __syncthreads();
    int nchunk = (n + 1023) / 1024;
    for (int c = 0; c < nchunk; ++c) {
        int idx = c * 1024 + threadIdx.x;
        int v = (idx < n) ? deg[idx] : 0;
        buf[threadIdx.x] = v;
        __syncthreads();
        for (int off = 1; off < 1024; off <<= 1) {
            int add = (threadIdx.x >= off) ? buf[threadIdx.x - off] : 0;
            __syncthreads();
            buf[threadIdx.x] += add;
            __syncthreads();
        }
        if (idx < n) rowp[idx] = carry + buf[threadIdx.x] - v;
        int total = buf[1023];
        __syncthreads();
        if (threadIdx.x == 0) carry += total;
        __syncthreads();
    }
    if (threadIdx.x == 0) rowp[n] = carry;
}

// ---- CSR fill ----
__global__ void k_fill(const int* e, const int* flags, const int* rowp,
                       int* cur, int* col, int E, int n) {
    int i = blockIdx.x * blockDim.x + threadIdx.x;
    if (i < E) {
        int is64 = (flags[1] == 0);
        int d = is64 ? e[2 * (E + i)] : e[E + i];
        int s = is64 ? e[2 * i] : e[i];
        if ((unsigned)d < (unsigned)n) {
            int p = rowp[d] + atomicAdd(&cur[d], 1);
            if ((unsigned)p < (unsigned)E) {
                if ((unsigned)s >= (unsigned)n) s = 0;
                col[p] = s;
            }
        }
    }
}

// ---- CSR mean gather: M[row] = mean of neighbor rows, bf16-packed u32 ----
// one wave per row; lane L covers elems {2L, 2L+1}
__global__ void k_gather(const int* rowp, const int* col, const void* hin,
                         const int* hflagp, unsigned int* M, int n) {
    int row = blockIdx.x * 4 + (threadIdx.x >> 6);
    int L = threadIdx.x & 63;
    if (row >= n) return;
    int hf32 = *hflagp;
    int b = rowp[row], e = rowp[row + 1];
    float s0 = 0.f, s1 = 0.f;
    if (hf32) {
        const float* hp = (const float*)hin;
        for (int p = b; p < e; ++p) {
            int s = col[p];
            float2 v = *(const float2*)(hp + (size_t)s * DN + 2 * L);
            s0 += v.x; s1 += v.y;
        }
    } else {
        const unsigned int* hp = (const unsigned int*)hin;
        for (int p = b; p < e; ++p) {
            int s = col[p];
            unsigned int u = hp[(size_t)s * 64 + L];
            s0 += lo16(u); s1 += hi16(u);
        }
    }
    int d = e - b; if (d < 1) d = 1;
    float inv = 1.0f / (float)d;
    M[(size_t)row * 64 + L] = pack2(s0 * inv, s1 * inv);
}

// ---- GEMM: out = relu([M | h] @ [Wl|Wr]^T + bias), bf16 math, no spill ----
// block 256 = 4 waves; 64 rows per block; wave processes 2 rows at a time.
// sWp[j*128+c] = packed (W'[c][2j], W'[c][2j+1]), j in [0,128) over K=256. 64 KB.
// Safe when hout aliases hin (self-row reads only; M is separate).
__global__ void k_gemm(const unsigned int* M, const void* hin, const int* hflagp,
                       const void* Wl, const void* Wr, const void* bias,
                       const int* wflagp, unsigned short* hout, int n) {
    __shared__ unsigned int sWp[128 * 128];
    const int t = threadIdx.x;
    const int wf32 = *wflagp;
    const int hf32 = *hflagp;

    // stage packed weights
    {
        int jj = t & 63, cb = t >> 6;
        for (int half = 0; half < 2; ++half) {
            const void* W = half ? Wr : Wl;
            for (int it = 0; it < 32; ++it) {
                int c = it * 4 + cb;
                float w0, w1;
                if (wf32) {
                    float2 v = *(const float2*)((const float*)W + (size_t)c * DN + 2 * jj);
                    w0 = v.x; w1 = v.y;
                } else {
                    unsigned int u = ((const unsigned int*)W)[(size_t)c * 64 + jj];
                    w0 = lo16(u); w1 = hi16(u);
                }
                sWp[(half * 64 + jj) * 128 + c] = pack2(w0, w1);
            }
        }
    }
    __syncthreads();

    const int L = t & 63, wv = t >> 6;
    float bs0 = ldx(bias, L, wf32);
    float bs1 = ldx(bias, 64 + L, wf32);
    const int i0 = blockIdx.x * 64;

    for (int it = 0; it < 8; ++it) {
        int iA = i0 + wv + 8 * it;
        int iB = iA + 4;
        bool vA = iA < n, vB = iB < n;
        unsigned int mA = vA ? M[(size_t)iA * 64 + L] : 0u;
        unsigned int mB = vB ? M[(size_t)iB * 64 + L] : 0u;
        unsigned int sA, sB;
        if (hf32) {
            const float* hp = (const float*)hin;
            float ax = 0.f, ay = 0.f, bx = 0.f, by = 0.f;
            if (vA) { float2 v = *(const float2*)(hp + (size_t)iA * DN + 2 * L); ax = v.x; ay = v.y; }
            if (vB) { float2 v = *(const float2*)(hp + (size_t)iB * DN + 2 * L); bx = v.x; by = v.y; }
            sA = pack2(ax, ay); sB = pack2(bx, by);
        } else {
            const unsigned int* hp = (const unsigned int*)hin;
            sA = vA ? hp[(size_t)iA * 64 + L] : 0u;
            sB = vB ? hp[(size_t)iB * 64 + L] : 0u;
        }
        float acc0A = 0.f, acc1A = 0.f, acc0B = 0.f, acc1B = 0.f;
        // K-half 0: mean part (j-pairs 0..63)
#pragma unroll
        for (int j = 0; j < 64; ++j) {
            unsigned int wp0 = sWp[j * 128 + L];
            unsigned int wp1 = sWp[j * 128 + 64 + L];
            unsigned int ba = __shfl(mA, j, 64);
            unsigned int bb = __shfl(mB, j, 64);
            float w00 = lo16(wp0), w01 = hi16(wp0);
            float w10 = lo16(wp1), w11 = hi16(wp1);
            float a0 = lo16(ba), a1 = hi16(ba);
            float b0 = lo16(bb), b1 = hi16(bb);
            acc0A += a0 * w00 + a1 * w01;
            acc1A += a0 * w10 + a1 * w11;
            acc0B += b0 * w00 + b1 * w01;
            acc1B += b0 * w10 + b1 * w11;
        }
        // K-half 1: self part (j-pairs 64..127)
#pragma unroll
        for (int j = 0; j < 64; ++j) {
            unsigned int wp0 = sWp[(64 + j) * 128 + L];
            unsigned int wp1 = sWp[(64 + j) * 128 + 64 + L];
            unsigned int ba = __shfl(sA, j, 64);
            unsigned int bb = __shfl(sB, j, 64);
            float w00 = lo16(wp0), w01 = hi16(wp0);
            float w10 = lo16(wp1), w11 = hi16(wp1);
            float a0 = lo16(ba), a1 = hi16(ba);
            float b0 = lo16(bb), b1 = hi16(bb);
            acc0A += a0 * w00 + a1 * w01;
            acc1A += a0 * w10 + a1 * w11;
            acc0B += b0 * w00 + b1 * w01;
            acc1B += b0 * w10 + b1 * w11;
        }
        if (vA) {
            float v0 = acc0A + bs0; v0 = (v0 > 0.f) ? v0 : 0.f;
            float v1 = acc1A + bs1; v1 = (v1 > 0.f) ? v1 : 0.f;
            hout[(size_t)iA * DN + L]      = f2bf(v0);
            hout[(size_t)iA * DN + 64 + L] = f2bf(v1);
        }
        if (vB) {
            float v0 = acc0B + bs0; v0 = (v0 > 0.f) ? v0 : 0.f;
            float v1 = acc1B + bs1; v1 = (v1 > 0.f) ? v1 : 0.f;
            hout[(size_t)iB * DN + L]      = f2bf(v0);
            hout[(size_t)iB * DN + 64 + L] = f2bf(v1);
        }
    }
}

// ---- LayerNorm: h (bf16) -> out (dtype per flags) ----
__global__ void k_ln(const unsigned short* h2, const void* w, const void* b,
                     void* out, int n, const int* flags) {
    int wave = blockIdx.x * (blockDim.x >> 6) + (threadIdx.x >> 6);
    int lane = threadIdx.x & 63;
    if (wave >= n) return;
    int wf32 = flags[2];
    int outf32 = (flags[0] && flags[2]);
    const unsigned short* row = h2 + (size_t)wave * DN;
    float a = bf2f(row[lane]);
    float c = bf2f(row[64 + lane]);
    float s = a + c;
#pragma unroll
    for (int off = 32; off; off >>= 1) s += __shfl_xor(s, off, 64);
    float mu = s * (1.0f / 128.0f);
    float da = a - mu, dc = c - mu;
    float q = da * da + dc * dc;
#pragma unroll
    for (int off = 32; off; off >>= 1) q += __shfl_xor(q, off, 64);
    float rs = rsqrtf(q * (1.0f / 128.0f) + 1e-5f);
    float o0 = da * rs * ldx(w, lane, wf32) + ldx(b, lane, wf32);
    float o1 = dc * rs * ldx(w, 64 + lane, wf32) + ldx(b, 64 + lane, wf32);
    size_t i0 = (size_t)wave * DN + lane;
    if (outf32) {
        ((float*)out)[i0] = o0;
        ((float*)out)[i0 + 64] = o1;
    } else {
        ((unsigned short*)out)[i0] = f2bf(o0);
        ((unsigned short*)out)[i0 + 64] = f2bf(o1);
    }
}

__global__ void k_mix(const int* flags, unsigned short* out, int cnt) {
    if (flags[0] == flags[2]) return;
    for (int i = blockIdx.x * blockDim.x + threadIdx.x; i < cnt; i += gridDim.x * blockDim.x)
        out[i] = 0x442F;
}

extern "C" void kernel_launch(void* const* d_in, const int* in_sizes, int n_in,
                              void* d_out, int out_size, void* d_ws, size_t ws_size,
                              hipStream_t stream) {
    const int N_EXP = 50000, E_EXP = 800000;

    const size_t sz_flags  = 256;
    const size_t sz_rowp   = (((size_t)(N_EXP + 1) * 4) + 255) & ~(size_t)255;
    const size_t sz_cursor = (((size_t)N_EXP * 4) + 255) & ~(size_t)255;
    const size_t sz_col    = (((size_t)E_EXP * 4) + 255) & ~(size_t)255;
    const size_t sz_M      = (size_t)N_EXP * 64 * 4;    // packed bf16 pairs
    const size_t sz_h      = (size_t)N_EXP * DN * 2;    // bf16
    const size_t need = sz_flags + sz_rowp + sz_cursor + sz_col + sz_M + sz_h;

    float diag = 0.f;
    if (in_sizes[0] != N_EXP * DN) diag += 1000.f;
    if (in_sizes[1] != 2 * E_EXP)  diag += 2000.f;
    if (n_in != 10)                diag += 4000.f;
    if (out_size != N_EXP * DN)    diag += 8000.f;
    if (ws_size < need)            diag += 16000.f;
    if (diag != 0.f) {
        k_diag<<<1024, 256, 0, stream>>>((unsigned short*)d_out, N_EXP * DN, diag);
        return;
    }

    const void* x   = d_in[0];
    const int*  ei  = (const int*)d_in[1];
    const void* W1l = d_in[2];
    const void* b1l = d_in[3];
    const void* W1r = d_in[4];
    const void* W2l = d_in[5];
    const void* b2l = d_in[6];
    const void* W2r = d_in[7];
    const void* lnw = d_in[8];
    const void* lnb = d_in[9];

    const int n = N_EXP, E = E_EXP;

    char* ws = (char*)d_ws;
    int* flags  = (int*)ws;
    int* rowp   = (int*)(ws + sz_flags);
    int* cursor = (int*)(ws + sz_flags + sz_rowp);
    int* col    = (int*)(ws + sz_flags + sz_rowp + sz_cursor);
    unsigned int*   M  = (unsigned int*)(ws + sz_flags + sz_rowp + sz_cursor + sz_col);
    unsigned short* h1 = (unsigned short*)(ws + sz_flags + sz_rowp + sz_cursor + sz_col + sz_M);

    hipMemsetAsync(flags, 0, sz_flags, stream);
    hipMemsetAsync(cursor, 0, (size_t)n * 4, stream);

    k_probe<<<1, 256, 0, stream>>>(x, W1l, ei, flags);
    k_mfma_probe<<<1, 64, 0, stream>>>((float*)(ws + 128));  // compile/run probe, dead scratch

    k_deg<<<(E + 255) / 256, 256, 0, stream>>>(ei, flags, cursor, E, n);
    k_scan<<<1, 1024, 0, stream>>>(cursor, rowp, n);
    hipMemsetAsync(cursor, 0, (size_t)n * 4, stream);
    k_fill<<<(E + 255) / 256, 256, 0, stream>>>(ei, flags, rowp, cursor, col, E, n);

    int gb = (n + 3) / 4;        // gather blocks
    int mb = (n + 63) / 64;      // gemm blocks

    // layer 1
    k_gather<<<gb, 256, 0, stream>>>(rowp, col, x, &flags[0], M, n);
    k_gemm<<<mb, 256, 0, stream>>>(M, x, &flags[0], W1l, W1r, b1l, &flags[2], h1, n);
    // layer 2 (gemm in-place on h1)
    k_gather<<<gb, 256, 0, stream>>>(rowp, col, h1, &flags[3], M, n);
    k_gemm<<<mb, 256, 0, stream>>>(M, h1, &flags[3], W2l, W2r, b2l, &flags[2], h1, n);
    // layernorm
    k_ln<<<(n + 3) / 4, 256, 0, stream>>>(h1, lnw, lnb, d_out, n, flags);
    k_mix<<<1024, 256, 0, stream>>>(flags, (unsigned short*)d_out, N_EXP * DN);
}

// Round 10
// 728.486 us; speedup vs baseline: 9.3095x; 9.3095x over previous
//
#include <hip/hip_runtime.h>

#define DN 128
#define LS 136   // LDS row stride in shorts (272 B = 68 u32 -> 4-bank rotation/row)

typedef short s16x8 __attribute__((ext_vector_type(8)));
typedef float f32x4 __attribute__((ext_vector_type(4)));

__device__ __forceinline__ float bf2f(unsigned short u) {
    union { unsigned int i; float f; } v; v.i = ((unsigned int)u) << 16; return v.f;
}
__device__ __forceinline__ unsigned short f2bf(float f) {
    union { float f; unsigned int i; } v; v.f = f;
    unsigned int r = v.i + 0x7fffu + ((v.i >> 16) & 1u);
    return (unsigned short)(r >> 16);
}
__device__ __forceinline__ float lo16(unsigned int u) { return bf2f((unsigned short)(u & 0xffffu)); }
__device__ __forceinline__ float hi16(unsigned int u) { return bf2f((unsigned short)(u >> 16)); }
__device__ __forceinline__ unsigned int pack2(float x, float y) {
    return (unsigned int)f2bf(x) | ((unsigned int)f2bf(y) << 16);
}
__device__ __forceinline__ float ldx(const void* p, size_t i, int f32) {
    return f32 ? ((const float*)p)[i] : bf2f(((const unsigned short*)p)[i]);
}

__global__ void k_diag(unsigned short* out, int cnt, float val) {
    unsigned short v = f2bf(val);
    for (int i = blockIdx.x * blockDim.x + threadIdx.x; i < cnt; i += gridDim.x * blockDim.x)
        out[i] = v;
}

// ---- dtype probes (flags pre-zeroed) ----
__global__ void k_probe(const void* x, const void* w, const int* e, int* flags) {
    int t = threadIdx.x;
    const unsigned short* xu = (const unsigned short*)x;
    for (int i = t; i < 100000; i += 256)
        if ((xu[i] & 0x7F80u) == 0x7F80u) { atomicOr(&flags[0], 1); break; }
    const unsigned short* wu = (const unsigned short*)w;
    for (int i = t; i < 16384; i += 256)
        if ((wu[i] & 0x7F80u) == 0x7F80u) { atomicOr(&flags[2], 1); break; }
    for (int i = t; i < 1000; i += 256)
        if (e[2 * i + 1] != 0) { atomicOr(&flags[1], 1); break; }
}

// ---- degree histogram ----
__global__ void k_deg(const int* e, const int* flags, int* deg, int E, int n) {
    int i = blockIdx.x * blockDim.x + threadIdx.x;
    if (i < E) {
        int is64 = (flags[1] == 0);
        int d = is64 ? e[2 * (E + i)] : e[E + i];
        if ((unsigned)d < (unsigned)n) atomicAdd(&deg[d], 1);
    }
}

// ---- parallel exclusive scan: 3 tiny kernels ----
__global__ void k_scan1(const int* deg, int* rowp, int* part, int n) {
    __shared__ int buf[1024];
    int idx = blockIdx.x * 1024 + threadIdx.x;
    int v = (idx < n) ? deg[idx] : 0;
    buf[threadIdx.x] = v;
    __syncthreads();
    for (int off = 1; off < 1024; off <<= 1) {
        int add = (threadIdx.x >= off) ? buf[threadIdx.x - off] : 0;
        __syncthreads();
        buf[threadIdx.x] += add;
        __syncthreads();
    }
    if (idx < n) rowp[idx] = buf[threadIdx.x] - v;    // block-local exclusive
    if (threadIdx.x == 1023) part[blockIdx.x] = buf[1023];
}
__global__ void k_scan2(int* part, int nb) {
    if (threadIdx.x == 0) {
        int c = 0;
        for (int i = 0; i < nb; ++i) { int v = part[i]; part[i] = c; c += v; }
        part[nb] = c;
    }
}
__global__ void k_scan3(int* rowp, const int* part, int n, int nb) {
    int idx = blockIdx.x * 1024 + threadIdx.x;
    if (idx < n) rowp[idx] += part[blockIdx.x];
    if (blockIdx.x == 0 && threadIdx.x == 0) rowp[n] = part[nb];
}

// ---- CSR fill ----
__global__ void k_fill(const int* e, const int* flags, const int* rowp,
                       int* cur, int* col, int E, int n) {
    int i = blockIdx.x * blockDim.x + threadIdx.x;
    if (i < E) {
        int is64 = (flags[1] == 0);
        int d = is64 ? e[2 * (E + i)] : e[E + i];
        int s = is64 ? e[2 * i] : e[i];
        if ((unsigned)d < (unsigned)n) {
            int p = rowp[d] + atomicAdd(&cur[d], 1);
            if ((unsigned)p < (unsigned)E) {
                if ((unsigned)s >= (unsigned)n) s = 0;
                col[p] = s;
            }
        }
    }
}

// ---- CSR mean gather -> M (bf16-packed u32), one wave per row ----
__global__ void k_gather(const int* rowp, const int* col, const void* hin,
                         const int* hflagp, unsigned int* M, int n) {
    int row = blockIdx.x * 4 + (threadIdx.x >> 6);
    int L = threadIdx.x & 63;
    if (row >= n) return;
    int hf32 = *hflagp;
    int b = rowp[row], e = rowp[row + 1];
    float s0 = 0.f, s1 = 0.f;
    if (hf32) {
        const float* hp = (const float*)hin;
        for (int p = b; p < e; ++p) {
            int s = col[p];
            float2 v = *(const float2*)(hp + (size_t)s * DN + 2 * L);
            s0 += v.x; s1 += v.y;
        }
    } else {
        const unsigned int* hp = (const unsigned int*)hin;
        for (int p = b; p < e; ++p) {
            int s = col[p];
            unsigned int u = hp[(size_t)s * 64 + L];
            s0 += lo16(u); s1 += hi16(u);
        }
    }
    int d = e - b; if (d < 1) d = 1;
    float inv = 1.0f / (float)d;
    M[(size_t)row * 64 + L] = pack2(s0 * inv, s1 * inv);
}

// ---- MFMA GEMM: out = relu([M | h] @ [Wl|Wr]^T + bias) ----
// block 256 = 4 waves; tile 64 rows x 128 cols; two K=128 phases (Wl then Wr).
// Safe when hout aliases hin (block reads only its own rows; M separate).
__global__ __launch_bounds__(256) void k_gemm(
        const unsigned int* M, const void* hin, const int* hflagp,
        const void* Wl, const void* Wr, const void* bias, const int* wflagp,
        unsigned short* hout, int n) {
    __shared__ unsigned short sA[64 * LS];    // 17 KB
    __shared__ unsigned short sB[128 * LS];   // 35 KB
    unsigned int* sAu = (unsigned int*)sA;
    unsigned int* sBu = (unsigned int*)sB;
    const int t = threadIdx.x;
    const int hf32 = *hflagp, wf32 = *wflagp;
    const int i0 = blockIdx.x * 64;
    const int lane = t & 63, wv = t >> 6, ln15 = lane & 15, quad = lane >> 4;

    f32x4 acc[8];
#pragma unroll
    for (int i = 0; i < 8; ++i) { f32x4 z = {0.f, 0.f, 0.f, 0.f}; acc[i] = z; }

    for (int phase = 0; phase < 2; ++phase) {
        // ---- stage A tile: 64 rows x 64 u32 (bf16 pairs) ----
        if (phase == 0) {
#pragma unroll
            for (int i = 0; i < 16; ++i) {
                int idx = t + i * 256, r = idx >> 6, c = idx & 63;
                int node = i0 + r;
                sAu[r * 68 + c] = (node < n) ? M[(size_t)node * 64 + c] : 0u;
            }
        } else if (hf32) {
            const float* hp = (const float*)hin;
#pragma unroll
            for (int i = 0; i < 16; ++i) {
                int idx = t + i * 256, r = idx >> 6, c = idx & 63;
                int node = i0 + r;
                unsigned int v = 0u;
                if (node < n) {
                    float2 f = *(const float2*)(hp + (size_t)node * DN + 2 * c);
                    v = pack2(f.x, f.y);
                }
                sAu[r * 68 + c] = v;
            }
        } else {
            const unsigned int* hp = (const unsigned int*)hin;
#pragma unroll
            for (int i = 0; i < 16; ++i) {
                int idx = t + i * 256, r = idx >> 6, c = idx & 63;
                int node = i0 + r;
                sAu[r * 68 + c] = (node < n) ? hp[(size_t)node * 64 + c] : 0u;
            }
        }
        // ---- stage B tile: 128 cols x 64 u32 ----
        const void* W = phase ? Wr : Wl;
        if (wf32) {
            const float* wp = (const float*)W;
#pragma unroll
            for (int i = 0; i < 32; ++i) {
                int idx = t + i * 256, r = idx >> 6, kk = idx & 63;
                float2 f = *(const float2*)(wp + (size_t)r * DN + 2 * kk);
                sBu[r * 68 + kk] = pack2(f.x, f.y);
            }
        } else {
            const unsigned int* wp = (const unsigned int*)W;
#pragma unroll
            for (int i = 0; i < 32; ++i) {
                int idx = t + i * 256, r = idx >> 6, kk = idx & 63;
                sBu[r * 68 + kk] = wp[(size_t)r * 64 + kk];
            }
        }
        __syncthreads();

        // ---- MFMA: 4 k-steps x 8 col-tiles ----
        const int mrow = wv * 16;
#pragma unroll
        for (int ks = 0; ks < 4; ++ks) {
            s16x8 a = *(const s16x8*)&sA[(mrow + ln15) * LS + ks * 32 + quad * 8];
#pragma unroll
            for (int nt = 0; nt < 8; ++nt) {
                s16x8 b = *(const s16x8*)&sB[(nt * 16 + ln15) * LS + ks * 32 + quad * 8];
                acc[nt] = __builtin_amdgcn_mfma_f32_16x16x32_bf16(a, b, acc[nt], 0, 0, 0);
            }
        }
        __syncthreads();
    }

    // ---- epilogue: bias + relu + bf16 store ----
    // C/D layout (16x16x32): col = lane&15, row = quad*4 + reg  [learn_hip m89]
#pragma unroll
    for (int nt = 0; nt < 8; ++nt) {
        int colv = nt * 16 + ln15;
        float bs = ldx(bias, colv, wf32);
#pragma unroll
        for (int r = 0; r < 4; ++r) {
            int node = i0 + wv * 16 + quad * 4 + r;
            if (node < n) {
                float v = acc[nt][r] + bs;
                v = (v > 0.f) ? v : 0.f;
                hout[(size_t)node * DN + colv] = f2bf(v);
            }
        }
    }
}

// ---- LayerNorm: h (bf16) -> out (dtype per flags) ----
__global__ void k_ln(const unsigned short* h2, const void* w, const void* b,
                     void* out, int n, const int* flags) {
    int wave = blockIdx.x * (blockDim.x >> 6) + (threadIdx.x >> 6);
    int lane = threadIdx.x & 63;
    if (wave >= n) return;
    int wf32 = flags[2];
    int outf32 = (flags[0] && flags[2]);
    const unsigned short* row = h2 + (size_t)wave * DN;
    float a = bf2f(row[lane]);
    float c = bf2f(row[64 + lane]);
    float s = a + c;
#pragma unroll
    for (int off = 32; off; off >>= 1) s += __shfl_xor(s, off, 64);
    float mu = s * (1.0f / 128.0f);
    float da = a - mu, dc = c - mu;
    float q = da * da + dc * dc;
#pragma unroll
    for (int off = 32; off; off >>= 1) q += __shfl_xor(q, off, 64);
    float rs = rsqrtf(q * (1.0f / 128.0f) + 1e-5f);
    float o0 = da * rs * ldx(w, lane, wf32) + ldx(b, lane, wf32);
    float o1 = dc * rs * ldx(w, 64 + lane, wf32) + ldx(b, 64 + lane, wf32);
    size_t i0 = (size_t)wave * DN + lane;
    if (outf32) {
        ((float*)out)[i0] = o0;
        ((float*)out)[i0 + 64] = o1;
    } else {
        ((unsigned short*)out)[i0] = f2bf(o0);
        ((unsigned short*)out)[i0 + 64] = f2bf(o1);
    }
}

__global__ void k_mix(const int* flags, unsigned short* out, int cnt) {
    if (flags[0] == flags[2]) return;
    for (int i = blockIdx.x * blockDim.x + threadIdx.x; i < cnt; i += gridDim.x * blockDim.x)
        out[i] = 0x442F;
}

extern "C" void kernel_launch(void* const* d_in, const int* in_sizes, int n_in,
                              void* d_out, int out_size, void* d_ws, size_t ws_size,
                              hipStream_t stream) {
    const int N_EXP = 50000, E_EXP = 800000;

    const size_t sz_flags  = 256;
    const size_t sz_rowp   = (((size_t)(N_EXP + 1) * 4) + 255) & ~(size_t)255;
    const size_t sz_cursor = (((size_t)N_EXP * 4) + 255) & ~(size_t)255;
    const size_t sz_col    = (((size_t)E_EXP * 4) + 255) & ~(size_t)255;
    const size_t sz_M      = (size_t)N_EXP * 64 * 4;
    const size_t sz_h      = (size_t)N_EXP * DN * 2;
    const size_t need = sz_flags + sz_rowp + sz_cursor + sz_col + sz_M + sz_h;

    float diag = 0.f;
    if (in_sizes[0] != N_EXP * DN) diag += 1000.f;
    if (in_sizes[1] != 2 * E_EXP)  diag += 2000.f;
    if (n_in != 10)                diag += 4000.f;
    if (out_size != N_EXP * DN)    diag += 8000.f;
    if (ws_size < need)            diag += 16000.f;
    if (diag != 0.f) {
        k_diag<<<1024, 256, 0, stream>>>((unsigned short*)d_out, N_EXP * DN, diag);
        return;
    }

    const void* x   = d_in[0];
    const int*  ei  = (const int*)d_in[1];
    const void* W1l = d_in[2];
    const void* b1l = d_in[3];
    const void* W1r = d_in[4];
    const void* W2l = d_in[5];
    const void* b2l = d_in[6];
    const void* W2r = d_in[7];
    const void* lnw = d_in[8];
    const void* lnb = d_in[9];

    const int n = N_EXP, E = E_EXP;

    char* ws = (char*)d_ws;
    int* flags  = (int*)ws;
    int* rowp   = (int*)(ws + sz_flags);
    int* cursor = (int*)(ws + sz_flags + sz_rowp);
    int* col    = (int*)(ws + sz_flags + sz_rowp + sz_cursor);
    unsigned int*   M  = (unsigned int*)(ws + sz_flags + sz_rowp + sz_cursor + sz_col);
    unsigned short* h1 = (unsigned short*)(ws + sz_flags + sz_rowp + sz_cursor + sz_col + sz_M);

    hipMemsetAsync(flags, 0, sz_flags, stream);
    hipMemsetAsync(cursor, 0, (size_t)n * 4, stream);

    k_probe<<<1, 256, 0, stream>>>(x, W1l, ei, flags);
    k_deg<<<(E + 255) / 256, 256, 0, stream>>>(ei, flags, cursor, E, n);

    // parallel scan; `part` borrows the (not-yet-written) col region
    int nb = (n + 1023) / 1024;   // 49
    int* part = col;
    k_scan1<<<nb, 1024, 0, stream>>>(cursor, rowp, part, n);
    k_scan2<<<1, 64, 0, stream>>>(part, nb);
    k_scan3<<<nb, 1024, 0, stream>>>(rowp, part, n, nb);

    hipMemsetAsync(cursor, 0, (size_t)n * 4, stream);
    k_fill<<<(E + 255) / 256, 256, 0, stream>>>(ei, flags, rowp, cursor, col, E, n);

    int gb = (n + 3) / 4;
    int mb = (n + 63) / 64;

    // layer 1
    k_gather<<<gb, 256, 0, stream>>>(rowp, col, x, &flags[0], M, n);
    k_gemm<<<mb, 256, 0, stream>>>(M, x, &flags[0], W1l, W1r, b1l, &flags[2], h1, n);
    // layer 2 (gemm in-place on h1)
    k_gather<<<gb, 256, 0, stream>>>(rowp, col, h1, &flags[3], M, n);
    k_gemm<<<mb, 256, 0, stream>>>(M, h1, &flags[3], W2l, W2r, b2l, &flags[2], h1, n);
    // layernorm
    k_ln<<<(n + 3) / 4, 256, 0, stream>>>(h1, lnw, lnb, d_out, n, flags);
    k_mix<<<1024, 256, 0, stream>>>(flags, (unsigned short*)d_out, N_EXP * DN);
}

// Round 11
// 440.507 us; speedup vs baseline: 15.3956x; 1.6537x over previous
//
#include <hip/hip_runtime.h>

#define DN 128
#define LS 136   // LDS row stride in shorts (272 B = 68 u32 -> 4-bank rotation/row)

typedef short s16x8 __attribute__((ext_vector_type(8)));
typedef float f32x4 __attribute__((ext_vector_type(4)));

__device__ __forceinline__ float bf2f(unsigned short u) {
    union { unsigned int i; float f; } v; v.i = ((unsigned int)u) << 16; return v.f;
}
__device__ __forceinline__ unsigned short f2bf(float f) {
    union { float f; unsigned int i; } v; v.f = f;
    unsigned int r = v.i + 0x7fffu + ((v.i >> 16) & 1u);
    return (unsigned short)(r >> 16);
}
__device__ __forceinline__ float lo16(unsigned int u) { return bf2f((unsigned short)(u & 0xffffu)); }
__device__ __forceinline__ float hi16(unsigned int u) { return bf2f((unsigned short)(u >> 16)); }
__device__ __forceinline__ unsigned int pack2(float x, float y) {
    return (unsigned int)f2bf(x) | ((unsigned int)f2bf(y) << 16);
}
__device__ __forceinline__ float ldx(const void* p, size_t i, int f32) {
    return f32 ? ((const float*)p)[i] : bf2f(((const unsigned short*)p)[i]);
}

__global__ void k_diag(unsigned short* out, int cnt, float val) {
    unsigned short v = f2bf(val);
    for (int i = blockIdx.x * blockDim.x + threadIdx.x; i < cnt; i += gridDim.x * blockDim.x)
        out[i] = v;
}

// ---- dtype probes, parallel (flags pre-zeroed); ranges safe for both dtypes ----
__global__ void k_probe(const void* x, const void* w, const int* e, int* flags) {
    int g = blockIdx.x * 256 + threadIdx.x;          // 0 .. 32767
    const unsigned short* xu = (const unsigned short*)x;
    int hitx = 0, hitw = 0, hite = 0;
    for (int i = g; i < 65536; i += 32768)           // x: first 65536 u16 words
        if ((xu[i] & 0x7F80u) == 0x7F80u) hitx = 1;
    const unsigned short* wu = (const unsigned short*)w;
    if (g < 16384 && (wu[g] & 0x7F80u) == 0x7F80u) hitw = 1;
    if (g < 1000 && e[2 * g + 1] != 0) hite = 1;
    if (hitx) atomicOr(&flags[0], 1);
    if (hitw) atomicOr(&flags[2], 1);
    if (hite) atomicOr(&flags[1], 1);
}

// ---- cast x -> bf16-packed u32 (plain copy if already bf16) ----
__global__ void k_cast(const void* x, const int* xflagp, unsigned int* xb, int cnt) {
    int i = blockIdx.x * blockDim.x + threadIdx.x;
    if (i >= cnt) return;
    if (*xflagp) {
        float2 v = *(const float2*)((const float*)x + 2 * (size_t)i);
        xb[i] = pack2(v.x, v.y);
    } else {
        xb[i] = ((const unsigned int*)x)[i];
    }
}

// ---- degree histogram ----
__global__ void k_deg(const int* e, const int* flags, int* deg, int E, int n) {
    int i = blockIdx.x * blockDim.x + threadIdx.x;
    if (i < E) {
        int is64 = (flags[1] == 0);
        int d = is64 ? e[2 * (E + i)] : e[E + i];
        if ((unsigned)d < (unsigned)n) atomicAdd(&deg[d], 1);
    }
}

// ---- parallel exclusive scan: 3 tiny kernels ----
__global__ void k_scan1(const int* deg, int* rowp, int* part, int n) {
    __shared__ int buf[1024];
    int idx = blockIdx.x * 1024 + threadIdx.x;
    int v = (idx < n) ? deg[idx] : 0;
    buf[threadIdx.x] = v;
    __syncthreads();
    for (int off = 1; off < 1024; off <<= 1) {
        int add = (threadIdx.x >= off) ? buf[threadIdx.x - off] : 0;
        __syncthreads();
        buf[threadIdx.x] += add;
        __syncthreads();
    }
    if (idx < n) rowp[idx] = buf[threadIdx.x] - v;
    if (threadIdx.x == 1023) part[blockIdx.x] = buf[1023];
}
__global__ void k_scan2(int* part, int nb) {
    if (threadIdx.x == 0) {
        int c = 0;
        for (int i = 0; i < nb; ++i) { int v = part[i]; part[i] = c; c += v; }
        part[nb] = c;
    }
}
__global__ void k_scan3(int* rowp, const int* part, int n, int nb) {
    int idx = blockIdx.x * 1024 + threadIdx.x;
    if (idx < n) rowp[idx] += part[blockIdx.x];
    if (blockIdx.x == 0 && threadIdx.x == 0) rowp[n] = part[nb];
}

// ---- CSR fill ----
__global__ void k_fill(const int* e, const int* flags, const int* rowp,
                       int* cur, int* col, int E, int n) {
    int i = blockIdx.x * blockDim.x + threadIdx.x;
    if (i < E) {
        int is64 = (flags[1] == 0);
        int d = is64 ? e[2 * (E + i)] : e[E + i];
        int s = is64 ? e[2 * i] : e[i];
        if ((unsigned)d < (unsigned)n) {
            int p = rowp[d] + atomicAdd(&cur[d], 1);
            if ((unsigned)p < (unsigned)E) {
                if ((unsigned)s >= (unsigned)n) s = 0;
                col[p] = s;
            }
        }
    }
}

// ---- CSR mean gather from bf16-packed rows -> M (bf16-packed u32) ----
// one wave per row; lane L covers elems {2L, 2L+1}
__global__ void k_gather(const int* rowp, const int* col, const unsigned int* hp,
                         unsigned int* M, int n) {
    int row = blockIdx.x * 4 + (threadIdx.x >> 6);
    int L = threadIdx.x & 63;
    if (row >= n) return;
    int b = rowp[row], e = rowp[row + 1];
    float s0 = 0.f, s1 = 0.f;
    for (int p = b; p < e; ++p) {
        int s = col[p];
        unsigned int u = hp[(size_t)s * 64 + L];
        s0 += lo16(u); s1 += hi16(u);
    }
    int d = e - b; if (d < 1) d = 1;
    float inv = 1.0f / (float)d;
    M[(size_t)row * 64 + L] = pack2(s0 * inv, s1 * inv);
}

// ---- MFMA GEMM: out = relu([M | h] @ [Wl|Wr]^T + bias), h bf16-packed ----
// block 256 = 4 waves; tile 64 rows x 128 cols; two K=128 phases (Wl then Wr).
// Safe when hout aliases hin (block reads only its own rows; M separate).
__global__ __launch_bounds__(256) void k_gemm(
        const unsigned int* M, const unsigned int* hin,
        const void* Wl, const void* Wr, const void* bias, const int* wflagp,
        unsigned int* hout, int n) {
    __shared__ unsigned short sA[64 * LS];    // 17 KB
    __shared__ unsigned short sB[128 * LS];   // 35 KB
    unsigned int* sAu = (unsigned int*)sA;
    unsigned int* sBu = (unsigned int*)sB;
    const int t = threadIdx.x;
    const int wf32 = *wflagp;
    const int i0 = blockIdx.x * 64;
    const int lane = t & 63, wv = t >> 6, ln15 = lane & 15, quad = lane >> 4;

    f32x4 acc[8];
#pragma unroll
    for (int i = 0; i < 8; ++i) { f32x4 z = {0.f, 0.f, 0.f, 0.f}; acc[i] = z; }

    for (int phase = 0; phase < 2; ++phase) {
        const unsigned int* A = phase ? hin : M;
#pragma unroll
        for (int i = 0; i < 16; ++i) {
            int idx = t + i * 256, r = idx >> 6, c = idx & 63;
            int node = i0 + r;
            sAu[r * 68 + c] = (node < n) ? A[(size_t)node * 64 + c] : 0u;
        }
        const void* W = phase ? Wr : Wl;
        if (wf32) {
            const float* wp = (const float*)W;
#pragma unroll
            for (int i = 0; i < 32; ++i) {
                int idx = t + i * 256, r = idx >> 6, kk = idx & 63;
                float2 f = *(const float2*)(wp + (size_t)r * DN + 2 * kk);
                sBu[r * 68 + kk] = pack2(f.x, f.y);
            }
        } else {
            const unsigned int* wp = (const unsigned int*)W;
#pragma unroll
            for (int i = 0; i < 32; ++i) {
                int idx = t + i * 256, r = idx >> 6, kk = idx & 63;
                sBu[r * 68 + kk] = wp[(size_t)r * 64 + kk];
            }
        }
        __syncthreads();

        const int mrow = wv * 16;
#pragma unroll
        for (int ks = 0; ks < 4; ++ks) {
            s16x8 a = *(const s16x8*)&sA[(mrow + ln15) * LS + ks * 32 + quad * 8];
#pragma unroll
            for (int nt = 0; nt < 8; ++nt) {
                s16x8 b = *(const s16x8*)&sB[(nt * 16 + ln15) * LS + ks * 32 + quad * 8];
                acc[nt] = __builtin_amdgcn_mfma_f32_16x16x32_bf16(a, b, acc[nt], 0, 0, 0);
            }
        }
        __syncthreads();
    }

    // epilogue: bias + relu + packed bf16 store
    // C/D layout (16x16x32): col = lane&15, row = quad*4 + reg  [learn_hip m89]
    __shared__ float sOut[4][16][17];   // per-wave transpose buffer? -> simple path: direct u16 stores
#pragma unroll
    for (int nt = 0; nt < 8; ++nt) {
        int colv = nt * 16 + ln15;
        float bs = ldx(bias, colv, wf32);
#pragma unroll
        for (int r = 0; r < 4; ++r) {
            int node = i0 + wv * 16 + quad * 4 + r;
            if (node < n) {
                float v = acc[nt][r] + bs;
                v = (v > 0.f) ? v : 0.f;
                ((unsigned short*)hout)[(size_t)node * DN + colv] = f2bf(v);
            }
        }
    }
    (void)sOut;
}

// ---- LayerNorm: h (bf16-packed) -> out (dtype per flags) ----
__global__ void k_ln(const unsigned int* h2, const void* w, const void* b,
                     void* out, int n, const int* flags) {
    int wave = blockIdx.x * (blockDim.x >> 6) + (threadIdx.x >> 6);
    int lane = threadIdx.x & 63;
    if (wave >= n) return;
    int wf32 = flags[2];
    int outf32 = (flags[0] && flags[2]);
    unsigned int u = h2[(size_t)wave * 64 + lane];
    float a = lo16(u), c = hi16(u);
    float s = a + c;
#pragma unroll
    for (int off = 32; off; off >>= 1) s += __shfl_xor(s, off, 64);
    float mu = s * (1.0f / 128.0f);
    float da = a - mu, dc = c - mu;
    float q = da * da + dc * dc;
#pragma unroll
    for (int off = 32; off; off >>= 1) q += __shfl_xor(q, off, 64);
    float rs = rsqrtf(q * (1.0f / 128.0f) + 1e-5f);
    float o0 = da * rs * ldx(w, 2 * lane, wf32) + ldx(b, 2 * lane, wf32);
    float o1 = dc * rs * ldx(w, 2 * lane + 1, wf32) + ldx(b, 2 * lane + 1, wf32);
    if (outf32) {
        float2* op = (float2*)out;
        float2 v; v.x = o0; v.y = o1;
        op[(size_t)wave * 64 + lane] = v;
    } else {
        ((unsigned int*)out)[(size_t)wave * 64 + lane] = pack2(o0, o1);
    }
}

__global__ void k_mix(const int* flags, unsigned short* out, int cnt) {
    if (flags[0] == flags[2]) return;
    for (int i = blockIdx.x * blockDim.x + threadIdx.x; i < cnt; i += gridDim.x * blockDim.x)
        out[i] = 0x442F;
}

extern "C" void kernel_launch(void* const* d_in, const int* in_sizes, int n_in,
                              void* d_out, int out_size, void* d_ws, size_t ws_size,
                              hipStream_t stream) {
    const int N_EXP = 50000, E_EXP = 800000;

    const size_t sz_flags  = 256;
    const size_t sz_rowp   = (((size_t)(N_EXP + 1) * 4) + 255) & ~(size_t)255;
    const size_t sz_cursor = (((size_t)N_EXP * 4) + 255) & ~(size_t)255;
    const size_t sz_col    = (((size_t)E_EXP * 4) + 255) & ~(size_t)255;
    const size_t sz_M      = (size_t)N_EXP * 64 * 4;
    const size_t sz_h      = (size_t)N_EXP * DN * 2;
    const size_t need = sz_flags + sz_rowp + sz_cursor + sz_col + sz_M + sz_h;

    float diag = 0.f;
    if (in_sizes[0] != N_EXP * DN) diag += 1000.f;
    if (in_sizes[1] != 2 * E_EXP)  diag += 2000.f;
    if (n_in != 10)                diag += 4000.f;
    if (out_size != N_EXP * DN)    diag += 8000.f;
    if (ws_size < need)            diag += 16000.f;
    if (diag != 0.f) {
        k_diag<<<1024, 256, 0, stream>>>((unsigned short*)d_out, N_EXP * DN, diag);
        return;
    }

    const void* x   = d_in[0];
    const int*  ei  = (const int*)d_in[1];
    const void* W1l = d_in[2];
    const void* b1l = d_in[3];
    const void* W1r = d_in[4];
    const void* W2l = d_in[5];
    const void* b2l = d_in[6];
    const void* W2r = d_in[7];
    const void* lnw = d_in[8];
    const void* lnb = d_in[9];

    const int n = N_EXP, E = E_EXP;

    char* ws = (char*)d_ws;
    int* flags  = (int*)ws;
    int* rowp   = (int*)(ws + sz_flags);
    int* cursor = (int*)(ws + sz_flags + sz_rowp);
    int* col    = (int*)(ws + sz_flags + sz_rowp + sz_cursor);
    unsigned int* M  = (unsigned int*)(ws + sz_flags + sz_rowp + sz_cursor + sz_col);
    unsigned int* h1 = (unsigned int*)(ws + sz_flags + sz_rowp + sz_cursor + sz_col + sz_M);

    hipMemsetAsync(flags, 0, sz_flags, stream);
    hipMemsetAsync(cursor, 0, (size_t)n * 4, stream);

    k_probe<<<128, 256, 0, stream>>>(x, W1l, ei, flags);
    k_deg<<<(E + 255) / 256, 256, 0, stream>>>(ei, flags, cursor, E, n);

    int nb = (n + 1023) / 1024;   // 49
    int* part = col;              // borrows not-yet-written col region
    k_scan1<<<nb, 1024, 0, stream>>>(cursor, rowp, part, n);
    k_scan2<<<1, 64, 0, stream>>>(part, nb);
    k_scan3<<<nb, 1024, 0, stream>>>(rowp, part, n, nb);

    hipMemsetAsync(cursor, 0, (size_t)n * 4, stream);
    k_fill<<<(E + 255) / 256, 256, 0, stream>>>(ei, flags, rowp, cursor, col, E, n);

    // cast x -> bf16 packed into h1 (layer-1 runs entirely on bf16)
    int cc = n * 64;
    k_cast<<<(cc + 255) / 256, 256, 0, stream>>>(x, &flags[0], h1, cc);

    int gb = (n + 3) / 4;
    int mb = (n + 63) / 64;

    // layer 1 (in-place on h1)
    k_gather<<<gb, 256, 0, stream>>>(rowp, col, h1, M, n);
    k_gemm<<<mb, 256, 0, stream>>>(M, h1, W1l, W1r, b1l, &flags[2], h1, n);
    // layer 2 (in-place on h1)
    k_gather<<<gb, 256, 0, stream>>>(rowp, col, h1, M, n);
    k_gemm<<<mb, 256, 0, stream>>>(M, h1, W2l, W2r, b2l, &flags[2], h1, n);
    // layernorm
    k_ln<<<(n + 3) / 4, 256, 0, stream>>>(h1, lnw, lnb, d_out, n, flags);
    k_mix<<<1024, 256, 0, stream>>>(flags, (unsigned short*)d_out, N_EXP * DN);
}

// Round 13
// 394.610 us; speedup vs baseline: 17.1863x; 1.1163x over previous
//
#include <hip/hip_runtime.h>

#define DN 128
#define LS 136   // LDS row stride in shorts (272 B = 68 u32 -> 4-bank rotation/row)

typedef short s16x8 __attribute__((ext_vector_type(8)));
typedef float f32x4 __attribute__((ext_vector_type(4)));

__device__ __forceinline__ float bf2f(unsigned short u) {
    union { unsigned int i; float f; } v; v.i = ((unsigned int)u) << 16; return v.f;
}
__device__ __forceinline__ unsigned short f2bf(float f) {
    union { float f; unsigned int i; } v; v.f = f;
    unsigned int r = v.i + 0x7fffu + ((v.i >> 16) & 1u);
    return (unsigned short)(r >> 16);
}
__device__ __forceinline__ float lo16(unsigned int u) { return bf2f((unsigned short)(u & 0xffffu)); }
__device__ __forceinline__ float hi16(unsigned int u) { return bf2f((unsigned short)(u >> 16)); }
__device__ __forceinline__ unsigned int pack2(float x, float y) {
    return (unsigned int)f2bf(x) | ((unsigned int)f2bf(y) << 16);
}
__device__ __forceinline__ float ldx(const void* p, size_t i, int f32) {
    return f32 ? ((const float*)p)[i] : bf2f(((const unsigned short*)p)[i]);
}

__global__ void k_diag(unsigned short* out, int cnt, float val) {
    unsigned short v = f2bf(val);
    for (int i = blockIdx.x * blockDim.x + threadIdx.x; i < cnt; i += gridDim.x * blockDim.x)
        out[i] = v;
}

// ---- dtype probes, parallel (flags pre-zeroed) ----
__global__ void k_probe(const void* x, const void* w, const int* e, int* flags) {
    int g = blockIdx.x * 256 + threadIdx.x;          // 0 .. 32767
    const unsigned short* xu = (const unsigned short*)x;
    int hitx = 0, hitw = 0, hite = 0;
    for (int i = g; i < 65536; i += 32768)
        if ((xu[i] & 0x7F80u) == 0x7F80u) hitx = 1;
    const unsigned short* wu = (const unsigned short*)w;
    if (g < 16384 && (wu[g] & 0x7F80u) == 0x7F80u) hitw = 1;
    if (g < 1000 && e[2 * g + 1] != 0) hite = 1;
    if (hitx) atomicOr(&flags[0], 1);
    if (hitw) atomicOr(&flags[2], 1);
    if (hite) atomicOr(&flags[1], 1);
}

// ---- cast x -> bf16-packed u32 ----
__global__ void k_cast(const void* x, const int* xflagp, unsigned int* xb, int cnt) {
    int i = blockIdx.x * blockDim.x + threadIdx.x;
    if (i >= cnt) return;
    if (*xflagp) {
        float2 v = *(const float2*)((const float*)x + 2 * (size_t)i);
        xb[i] = pack2(v.x, v.y);
    } else {
        xb[i] = ((const unsigned int*)x)[i];
    }
}

// ---- degree histogram ----
__global__ void k_deg(const int* e, const int* flags, int* deg, int E, int n) {
    int i = blockIdx.x * blockDim.x + threadIdx.x;
    if (i < E) {
        int is64 = (flags[1] == 0);
        int d = is64 ? e[2 * (E + i)] : e[E + i];
        if ((unsigned)d < (unsigned)n) atomicAdd(&deg[d], 1);
    }
}

// ---- parallel exclusive scan ----
__global__ void k_scan1(const int* deg, int* rowp, int* part, int n) {
    __shared__ int buf[1024];
    int idx = blockIdx.x * 1024 + threadIdx.x;
    int v = (idx < n) ? deg[idx] : 0;
    buf[threadIdx.x] = v;
    __syncthreads();
    for (int off = 1; off < 1024; off <<= 1) {
        int add = (threadIdx.x >= off) ? buf[threadIdx.x - off] : 0;
        __syncthreads();
        buf[threadIdx.x] += add;
        __syncthreads();
    }
    if (idx < n) rowp[idx] = buf[threadIdx.x] - v;
    if (threadIdx.x == 1023) part[blockIdx.x] = buf[1023];
}
__global__ void k_scan2(int* part, int nb) {
    if (threadIdx.x == 0) {
        int c = 0;
        for (int i = 0; i < nb; ++i) { int v = part[i]; part[i] = c; c += v; }
        part[nb] = c;
    }
}
__global__ void k_scan3(int* rowp, const int* part, int n, int nb) {
    int idx = blockIdx.x * 1024 + threadIdx.x;
    if (idx < n) rowp[idx] += part[blockIdx.x];
    if (blockIdx.x == 0 && threadIdx.x == 0) rowp[n] = part[nb];
}

// ---- CSR fill ----
__global__ void k_fill(const int* e, const int* flags, const int* rowp,
                       int* cur, int* col, int E, int n) {
    int i = blockIdx.x * blockDim.x + threadIdx.x;
    if (i < E) {
        int is64 = (flags[1] == 0);
        int d = is64 ? e[2 * (E + i)] : e[E + i];
        int s = is64 ? e[2 * i] : e[i];
        if ((unsigned)d < (unsigned)n) {
            int p = rowp[d] + atomicAdd(&cur[d], 1);
            if ((unsigned)p < (unsigned)E) {
                if ((unsigned)s >= (unsigned)n) s = 0;
                col[p] = s;
            }
        }
    }
}

// ---- CSR mean gather: bit-identical accumulation to R11, ids via shfl broadcast ----
// one wave per row; lane L covers elements {2L, 2L+1}. Neighbor ids preloaded
// 64-at-a-time lane-parallel, broadcast with wave-uniform shfl -> feature loads
// for successive j are address-independent (MLP hides L2 latency). Summation
// order identical to R11 (sequential over CSR-order neighbors).
__global__ void k_gather(const int* rowp, const int* col, const unsigned int* hp,
                         unsigned int* M, int n) {
    int row = blockIdx.x * 4 + (threadIdx.x >> 6);
    if (row >= n) return;
    const int L = threadIdx.x & 63;
    int b = rowp[row], e = rowp[row + 1];
    float s0 = 0.f, s1 = 0.f;
    for (int base = b; base < e; base += 64) {
        int cnt = e - base; if (cnt > 64) cnt = 64;
        int myc = (L < cnt) ? col[base + L] : 0;
        for (int j = 0; j < cnt; ++j) {
            int s = __shfl(myc, j, 64);
            unsigned int u = hp[(size_t)s * 64 + L];
            s0 += lo16(u); s1 += hi16(u);
        }
    }
    int d = e - b; if (d < 1) d = 1;
    float inv = 1.0f / (float)d;
    M[(size_t)row * 64 + L] = pack2(s0 * inv, s1 * inv);
}

// ---- MFMA GEMM: out = relu([M | h] @ [Wl|Wr]^T + bias) ----
// block 256 = 4 waves; tile 64 rows x 128 cols; two K=128 phases (Wl then Wr).
// Safe when hout aliases hin (block reads only its own rows; M separate).
__global__ __launch_bounds__(256) void k_gemm(
        const unsigned int* M, const unsigned int* hin,
        const void* Wl, const void* Wr, const void* bias, const int* wflagp,
        unsigned int* hout, int n) {
    __shared__ unsigned short sA[64 * LS];    // 17 KB
    __shared__ unsigned short sB[128 * LS];   // 35 KB
    unsigned int* sAu = (unsigned int*)sA;
    unsigned int* sBu = (unsigned int*)sB;
    const int t = threadIdx.x;
    const int wf32 = *wflagp;
    const int i0 = blockIdx.x * 64;
    const int lane = t & 63, wv = t >> 6, ln15 = lane & 15, quad = lane >> 4;

    f32x4 acc[8];
#pragma unroll
    for (int i = 0; i < 8; ++i) { f32x4 z = {0.f, 0.f, 0.f, 0.f}; acc[i] = z; }

    for (int phase = 0; phase < 2; ++phase) {
        const unsigned int* A = phase ? hin : M;
#pragma unroll
        for (int i = 0; i < 16; ++i) {
            int idx = t + i * 256, r = idx >> 6, c = idx & 63;
            int node = i0 + r;
            sAu[r * 68 + c] = (node < n) ? A[(size_t)node * 64 + c] : 0u;
        }
        const void* W = phase ? Wr : Wl;
        if (wf32) {
            const float* wp = (const float*)W;
#pragma unroll
            for (int i = 0; i < 32; ++i) {
                int idx = t + i * 256, r = idx >> 6, kk = idx & 63;
                float2 f = *(const float2*)(wp + (size_t)r * DN + 2 * kk);
                sBu[r * 68 + kk] = pack2(f.x, f.y);
            }
        } else {
            const unsigned int* wp = (const unsigned int*)W;
#pragma unroll
            for (int i = 0; i < 32; ++i) {
                int idx = t + i * 256, r = idx >> 6, kk = idx & 63;
                sBu[r * 68 + kk] = wp[(size_t)r * 64 + kk];
            }
        }
        __syncthreads();

        const int mrow = wv * 16;
#pragma unroll
        for (int ks = 0; ks < 4; ++ks) {
            s16x8 a = *(const s16x8*)&sA[(mrow + ln15) * LS + ks * 32 + quad * 8];
#pragma unroll
            for (int nt = 0; nt < 8; ++nt) {
                s16x8 b = *(const s16x8*)&sB[(nt * 16 + ln15) * LS + ks * 32 + quad * 8];
                acc[nt] = __builtin_amdgcn_mfma_f32_16x16x32_bf16(a, b, acc[nt], 0, 0, 0);
            }
        }
        __syncthreads();
    }

    // epilogue: bias + relu + bf16 store
    // C/D layout (16x16x32): col = lane&15, row = quad*4 + reg  [learn_hip m89]
#pragma unroll
    for (int nt = 0; nt < 8; ++nt) {
        int colv = nt * 16 + ln15;
        float bs = ldx(bias, colv, wf32);
#pragma unroll
        for (int r = 0; r < 4; ++r) {
            int node = i0 + wv * 16 + quad * 4 + r;
            if (node < n) {
                float v = acc[nt][r] + bs;
                v = (v > 0.f) ? v : 0.f;
                ((unsigned short*)hout)[(size_t)node * DN + colv] = f2bf(v);
            }
        }
    }
}

// ---- LayerNorm: h (bf16-packed) -> out (dtype per flags) ----
__global__ void k_ln(const unsigned int* h2, const void* w, const void* b,
                     void* out, int n, const int* flags) {
    int wave = blockIdx.x * (blockDim.x >> 6) + (threadIdx.x >> 6);
    int lane = threadIdx.x & 63;
    if (wave >= n) return;
    int wf32 = flags[2];
    int outf32 = (flags[0] && flags[2]);
    unsigned int u = h2[(size_t)wave * 64 + lane];
    float a = lo16(u), c = hi16(u);
    float s = a + c;
#pragma unroll
    for (int off = 32; off; off >>= 1) s += __shfl_xor(s, off, 64);
    float mu = s * (1.0f / 128.0f);
    float da = a - mu, dc = c - mu;
    float q = da * da + dc * dc;
#pragma unroll
    for (int off = 32; off; off >>= 1) q += __shfl_xor(q, off, 64);
    float rs = rsqrtf(q * (1.0f / 128.0f) + 1e-5f);
    float o0 = da * rs * ldx(w, 2 * lane, wf32) + ldx(b, 2 * lane, wf32);
    float o1 = dc * rs * ldx(w, 2 * lane + 1, wf32) + ldx(b, 2 * lane + 1, wf32);
    if (outf32) {
        float2 v; v.x = o0; v.y = o1;
        ((float2*)out)[(size_t)wave * 64 + lane] = v;
    } else {
        ((unsigned int*)out)[(size_t)wave * 64 + lane] = pack2(o0, o1);
    }
}

__global__ void k_mix(const int* flags, unsigned short* out, int cnt) {
    if (flags[0] == flags[2]) return;
    for (int i = blockIdx.x * blockDim.x + threadIdx.x; i < cnt; i += gridDim.x * blockDim.x)
        out[i] = 0x442F;
}

extern "C" void kernel_launch(void* const* d_in, const int* in_sizes, int n_in,
                              void* d_out, int out_size, void* d_ws, size_t ws_size,
                              hipStream_t stream) {
    const int N_EXP = 50000, E_EXP = 800000;

    const size_t sz_flags  = 256;
    const size_t sz_rowp   = (((size_t)(N_EXP + 1) * 4) + 255) & ~(size_t)255;
    const size_t sz_cursor = (((size_t)N_EXP * 4) + 255) & ~(size_t)255;
    const size_t sz_col    = (((size_t)E_EXP * 4) + 255) & ~(size_t)255;
    const size_t sz_M      = (size_t)N_EXP * 64 * 4;
    const size_t sz_h      = (size_t)N_EXP * DN * 2;
    const size_t need = sz_flags + sz_rowp + sz_cursor + sz_col + sz_M + sz_h;

    float diag = 0.f;
    if (in_sizes[0] != N_EXP * DN) diag += 1000.f;
    if (in_sizes[1] != 2 * E_EXP)  diag += 2000.f;
    if (n_in != 10)                diag += 4000.f;
    if (out_size != N_EXP * DN)    diag += 8000.f;
    if (ws_size < need)            diag += 16000.f;
    if (diag != 0.f) {
        k_diag<<<1024, 256, 0, stream>>>((unsigned short*)d_out, N_EXP * DN, diag);
        return;
    }

    const void* x   = d_in[0];
    const int*  ei  = (const int*)d_in[1];
    const void* W1l = d_in[2];
    const void* b1l = d_in[3];
    const void* W1r = d_in[4];
    const void* W2l = d_in[5];
    const void* b2l = d_in[6];
    const void* W2r = d_in[7];
    const void* lnw = d_in[8];
    const void* lnb = d_in[9];

    const int n = N_EXP, E = E_EXP;

    char* ws = (char*)d_ws;
    int* flags  = (int*)ws;
    int* rowp   = (int*)(ws + sz_flags);
    int* cursor = (int*)(ws + sz_flags + sz_rowp);
    int* col    = (int*)(ws + sz_flags + sz_rowp + sz_cursor);
    unsigned int* M  = (unsigned int*)(ws + sz_flags + sz_rowp + sz_cursor + sz_col);
    unsigned int* h1 = (unsigned int*)(ws + sz_flags + sz_rowp + sz_cursor + sz_col + sz_M);

    hipMemsetAsync(flags, 0, sz_flags, stream);
    hipMemsetAsync(cursor, 0, (size_t)n * 4, stream);

    k_probe<<<128, 256, 0, stream>>>(x, W1l, ei, flags);
    k_deg<<<(E + 255) / 256, 256, 0, stream>>>(ei, flags, cursor, E, n);

    int nb = (n + 1023) / 1024;   // 49
    int* part = col;              // borrows not-yet-written col region
    k_scan1<<<nb, 1024, 0, stream>>>(cursor, rowp, part, n);
    k_scan2<<<1, 64, 0, stream>>>(part, nb);
    k_scan3<<<nb, 1024, 0, stream>>>(rowp, part, n, nb);

    hipMemsetAsync(cursor, 0, (size_t)n * 4, stream);
    k_fill<<<(E + 255) / 256, 256, 0, stream>>>(ei, flags, rowp, cursor, col, E, n);

    // cast x -> bf16 packed into h1 (layer-1 runs entirely on bf16)
    int cc = n * 64;
    k_cast<<<(cc + 255) / 256, 256, 0, stream>>>(x, &flags[0], h1, cc);

    int gb = (n + 3) / 4;
    int mb = (n + 63) / 64;

    // layer 1 (in-place on h1)
    k_gather<<<gb, 256, 0, stream>>>(rowp, col, h1, M, n);
    k_gemm<<<mb, 256, 0, stream>>>(M, h1, W1l, W1r, b1l, &flags[2], h1, n);
    // layer 2 (in-place on h1)
    k_gather<<<gb, 256, 0, stream>>>(rowp, col, h1, M, n);
    k_gemm<<<mb, 256, 0, stream>>>(M, h1, W2l, W2r, b2l, &flags[2], h1, n);
    // layernorm
    k_ln<<<(n + 3) / 4, 256, 0, stream>>>(h1, lnw, lnb, d_out, n, flags);
    k_mix<<<1024, 256, 0, stream>>>(flags, (unsigned short*)d_out, N_EXP * DN);
}